// Round 1
// baseline (765.009 us; speedup 1.0000x reference)
//
#include <hip/hip_runtime.h>

// Problem constants
constexpr int B_ = 2, C_ = 64, H_ = 128, W_ = 128, HW_ = H_ * W_;
constexpr int OG_ = 8;          // offset groups == weight groups
constexpr float NEG_SLOPE = 0.1f;

// ---------------------------------------------------------------------------
// Kernel 1: deformable conv 3x3, groups=8, offset_groups=8, pad=1, stride=1.
// One thread per (b, group, pixel). Computes 8 output channels.
// ---------------------------------------------------------------------------
__global__ __launch_bounds__(256) void dcn_kernel(
    const float* __restrict__ x,      // [B,64,H,W]
    const float* __restrict__ off,    // [B,144,H,W]
    const float* __restrict__ wgt,    // [64,8,3,3]
    const float* __restrict__ bias,   // [64]
    float* __restrict__ aligned)      // [B,64,H,W]
{
    const int p = blockIdx.x * 256 + threadIdx.x;   // pixel index
    const int g = blockIdx.y;                        // group
    const int b = blockIdx.z;
    const int h = p >> 7;          // W = 128
    const int w = p & (W_ - 1);

    float acc[8];
#pragma unroll
    for (int o = 0; o < 8; ++o) acc[o] = bias[g * 8 + o];

    const float* offp = off + (size_t)b * 144 * HW_ + p;
    const float* xg   = x + ((size_t)b * C_ + g * 8) * HW_;

#pragma unroll
    for (int k = 0; k < 9; ++k) {
        const float dy = offp[(size_t)((g * 9 + k) * 2 + 0) * HW_];
        const float dx = offp[(size_t)((g * 9 + k) * 2 + 1) * HW_];
        const float py = (float)(h - 1 + k / 3) + dy;
        const float px = (float)(w - 1 + k % 3) + dx;
        const float y0f = floorf(py);
        const float x0f = floorf(px);
        const int y0 = (int)y0f, x0 = (int)x0f;
        const int y1 = y0 + 1,  x1 = x0 + 1;
        const float wy = py - y0f, wx = px - x0f;

        const bool vy0 = (unsigned)y0 < (unsigned)H_;
        const bool vy1 = (unsigned)y1 < (unsigned)H_;
        const bool vx0 = (unsigned)x0 < (unsigned)W_;
        const bool vx1 = (unsigned)x1 < (unsigned)W_;

        float f00 = (vy0 && vx0) ? (1.f - wy) * (1.f - wx) : 0.f;
        float f01 = (vy0 && vx1) ? (1.f - wy) * wx         : 0.f;
        float f10 = (vy1 && vx0) ? wy * (1.f - wx)         : 0.f;
        float f11 = (vy1 && vx1) ? wy * wx                 : 0.f;

        const int cy0 = min(max(y0, 0), H_ - 1);
        const int cy1 = min(max(y1, 0), H_ - 1);
        const int cx0 = min(max(x0, 0), W_ - 1);
        const int cx1 = min(max(x1, 0), W_ - 1);
        const int i00 = cy0 * W_ + cx0;
        const int i01 = cy0 * W_ + cx1;
        const int i10 = cy1 * W_ + cx0;
        const int i11 = cy1 * W_ + cx1;

#pragma unroll
        for (int i = 0; i < 8; ++i) {
            const float* xp = xg + (size_t)i * HW_;
            const float v = f00 * xp[i00] + f01 * xp[i01]
                          + f10 * xp[i10] + f11 * xp[i11];
#pragma unroll
            for (int o = 0; o < 8; ++o) {
                // wgt[(g*8+o)][i][k] — uniform index -> scalar load
                acc[o] = fmaf(wgt[((g * 8 + o) * 8 + i) * 9 + k], v, acc[o]);
            }
        }
    }

#pragma unroll
    for (int o = 0; o < 8; ++o)
        aligned[((size_t)b * C_ + g * 8 + o) * HW_ + p] = acc[o];
}

// ---------------------------------------------------------------------------
// Kernel 2/3: dense 3x3 conv, pad=1. Input = concat(in0[0:64], in1[0:64])
// when CIN==128, else in0 only. Each thread: one pixel, OCHUNK out-channels.
// Weights read with uniform indices -> scalar loads (free FMA operand).
// ---------------------------------------------------------------------------
template <int CIN, int OCHUNK, bool RESID>
__global__ __launch_bounds__(256) void conv3x3_kernel(
    const float* __restrict__ in0,
    const float* __restrict__ in1,
    const float* __restrict__ wgt,    // [64][CIN][3][3]
    const float* __restrict__ bias,   // [64]
    const float* __restrict__ resid,  // [B,64,H,W] or null
    float* __restrict__ out)          // [B,64,H,W]
{
    constexpr int NC = 4;                 // channels staged per iteration
    __shared__ float tile[NC][18][18];

    const int tid = threadIdx.x;
    const int ty = tid >> 4, tx = tid & 15;
    const int bx0 = blockIdx.x * 16;
    const int by0 = blockIdx.y * 16;
    const int zb = blockIdx.z;
    constexpr int NOC = 64 / OCHUNK;
    const int b   = zb / NOC;
    const int oc0 = (zb % NOC) * OCHUNK;

    float acc[OCHUNK];
#pragma unroll
    for (int o = 0; o < OCHUNK; ++o) acc[o] = 0.f;

    for (int c0 = 0; c0 < CIN; c0 += NC) {
        __syncthreads();
        for (int idx = tid; idx < NC * 324; idx += 256) {
            const int cc = idx / 324;
            const int r  = idx - cc * 324;
            const int sy = r / 18;
            const int sx = r - sy * 18;
            const int gy = by0 + sy - 1;
            const int gx = bx0 + sx - 1;
            const int c  = c0 + cc;
            float v = 0.f;
            if ((unsigned)gy < (unsigned)H_ && (unsigned)gx < (unsigned)W_) {
                const float* src = (CIN == 128 && c >= 64)
                    ? in1 + ((size_t)b * C_ + (c - 64)) * HW_
                    : in0 + ((size_t)b * C_ + c) * HW_;
                v = src[gy * W_ + gx];
            }
            tile[cc][sy][sx] = v;
        }
        __syncthreads();

#pragma unroll
        for (int cc = 0; cc < NC; ++cc) {
            float v[9];
#pragma unroll
            for (int k = 0; k < 9; ++k)
                v[k] = tile[cc][ty + k / 3][tx + k % 3];
            const float* wp = wgt + ((size_t)oc0 * CIN + (c0 + cc)) * 9;
#pragma unroll
            for (int o = 0; o < OCHUNK; ++o) {
#pragma unroll
                for (int k = 0; k < 9; ++k)
                    acc[o] = fmaf(wp[(size_t)o * CIN * 9 + k], v[k], acc[o]);
            }
        }
    }

    const int y = by0 + ty, xx = bx0 + tx;
    const size_t pix = (size_t)y * W_ + xx;
#pragma unroll
    for (int o = 0; o < OCHUNK; ++o) {
        float r = acc[o] + bias[oc0 + o];
        r = (r >= 0.f) ? r : NEG_SLOPE * r;
        const size_t oidx = ((size_t)b * C_ + oc0 + o) * HW_ + pix;
        if (RESID) r += resid[oidx];
        out[oidx] = r;
    }
}

// ---------------------------------------------------------------------------
extern "C" void kernel_launch(void* const* d_in, const int* in_sizes, int n_in,
                              void* d_out, int out_size, void* d_ws, size_t ws_size,
                              hipStream_t stream) {
    const float* x   = (const float*)d_in[0];   // previous_features [2,64,128,128]
    const float* off = (const float*)d_in[1];   // offsets [2,144,128,128]
    const float* dw  = (const float*)d_in[2];   // dcn_weight [64,8,3,3]
    const float* db  = (const float*)d_in[3];   // dcn_bias [64]
    const float* w1  = (const float*)d_in[4];   // [64,128,3,3]
    const float* b1  = (const float*)d_in[5];   // [64]
    const float* w2  = (const float*)d_in[6];   // [64,64,3,3]
    const float* b2  = (const float*)d_in[7];   // [64]
    float* out = (float*)d_out;

    float* aligned = (float*)d_ws;                          // 2*64*16384 floats = 8 MB
    float* t1      = aligned + (size_t)B_ * C_ * HW_;       // 8 MB

    // Stage 1: deformable conv -> aligned
    dcn_kernel<<<dim3(HW_ / 256, OG_, B_), 256, 0, stream>>>(x, off, dw, db, aligned);

    // Stage 2: conv1(concat(aligned, x)) + lrelu -> t1
    conv3x3_kernel<128, 32, false><<<dim3(W_ / 16, H_ / 16, B_ * 2), 256, 0, stream>>>(
        aligned, x, w1, b1, nullptr, t1);

    // Stage 3: conv2(t1) + lrelu + aligned -> out
    conv3x3_kernel<64, 32, true><<<dim3(W_ / 16, H_ / 16, B_ * 2), 256, 0, stream>>>(
        t1, nullptr, w2, b2, aligned, out);
}

// Round 2
// 137.383 us; speedup vs baseline: 5.5684x; 5.5684x over previous
//
#include <hip/hip_runtime.h>
#include <stdint.h>

typedef short short8 __attribute__((ext_vector_type(8)));
typedef float f32x4 __attribute__((ext_vector_type(4)));
typedef unsigned int u32x4 __attribute__((ext_vector_type(4)));
typedef unsigned int u32x2 __attribute__((ext_vector_type(2)));

constexpr int B_ = 2, C_ = 64, H_ = 128, W_ = 128, HW_ = H_ * W_;
constexpr float NEG_SLOPE = 0.1f;

__device__ inline unsigned short f2bf(float f) {
    union { float f; unsigned u; } c; c.f = f;
    unsigned r = c.u + 0x7FFFu + ((c.u >> 16) & 1u);   // RNE
    return (unsigned short)(r >> 16);
}
__device__ inline float bf2f(unsigned short s) {
    union { unsigned u; float f; } c; c.u = ((unsigned)s) << 16; return c.f;
}

// ---------------------------------------------------------------------------
// Weight repack: w[oc][ic][3][3] fp32 -> wr[oc][(icc*9+tap)*32 + ici] bf16
// ---------------------------------------------------------------------------
__global__ __launch_bounds__(256) void prep_weights(
    const float* __restrict__ w1, const float* __restrict__ w2,
    unsigned short* __restrict__ w1r, unsigned short* __restrict__ w2r)
{
    const int idx = blockIdx.x * 256 + threadIdx.x;
    if (idx < 64 * 1152) {
        int oc = idx / 1152, k = idx - oc * 1152;
        int kb = k >> 5, ici = k & 31, icc = kb / 9, tap = kb - icc * 9;
        w1r[idx] = f2bf(w1[(oc * 128 + icc * 32 + ici) * 9 + tap]);
    }
    if (idx < 64 * 576) {
        int oc = idx / 576, k = idx - oc * 576;
        int kb = k >> 5, ici = k & 31, icc = kb / 9, tap = kb - icc * 9;
        w2r[idx] = f2bf(w2[(oc * 64 + icc * 32 + ici) * 9 + tap]);
    }
}

// ---------------------------------------------------------------------------
// Deformable conv 3x3 (groups=8, offset_groups=8). Thread = (b, g, pixel),
// 8 out-channels. Writes in_cl[p][0:64]=bf16(aligned), in_cl[p][64:128]=bf16(x).
// ---------------------------------------------------------------------------
__global__ __launch_bounds__(256) void dcn_kernel(
    const float* __restrict__ x,      // [B,64,H,W]
    const float* __restrict__ off,    // [B,144,H,W]
    const float* __restrict__ wgt,    // [64,8,3,3]
    const float* __restrict__ bias,   // [64]
    unsigned short* __restrict__ in_cl) // [B][HW][128]
{
    const int p = blockIdx.x * 256 + threadIdx.x;
    const int g = blockIdx.y;
    const int b = blockIdx.z;
    const int h = p >> 7;
    const int w = p & (W_ - 1);

    float acc[8];
#pragma unroll
    for (int o = 0; o < 8; ++o) acc[o] = bias[g * 8 + o];

    const float* offp = off + (size_t)b * 144 * HW_ + p;
    const float* xg   = x + ((size_t)b * C_ + g * 8) * HW_;

#pragma unroll
    for (int k = 0; k < 9; ++k) {
        const float dy = offp[(size_t)((g * 9 + k) * 2 + 0) * HW_];
        const float dx = offp[(size_t)((g * 9 + k) * 2 + 1) * HW_];
        const float py = (float)(h - 1 + k / 3) + dy;
        const float px = (float)(w - 1 + k % 3) + dx;
        const float y0f = floorf(py), x0f = floorf(px);
        const int y0 = (int)y0f, x0 = (int)x0f;
        const int y1 = y0 + 1,  x1 = x0 + 1;
        const float wy = py - y0f, wx = px - x0f;

        const bool vy0 = (unsigned)y0 < (unsigned)H_;
        const bool vy1 = (unsigned)y1 < (unsigned)H_;
        const bool vx0 = (unsigned)x0 < (unsigned)W_;
        const bool vx1 = (unsigned)x1 < (unsigned)W_;

        float f00 = (vy0 && vx0) ? (1.f - wy) * (1.f - wx) : 0.f;
        float f01 = (vy0 && vx1) ? (1.f - wy) * wx         : 0.f;
        float f10 = (vy1 && vx0) ? wy * (1.f - wx)         : 0.f;
        float f11 = (vy1 && vx1) ? wy * wx                 : 0.f;

        const int cy0 = min(max(y0, 0), H_ - 1);
        const int cy1 = min(max(y1, 0), H_ - 1);
        const int cx0 = min(max(x0, 0), W_ - 1);
        const int cx1 = min(max(x1, 0), W_ - 1);
        const int i00 = cy0 * W_ + cx0;
        const int i01 = cy0 * W_ + cx1;
        const int i10 = cy1 * W_ + cx0;
        const int i11 = cy1 * W_ + cx1;

#pragma unroll
        for (int i = 0; i < 8; ++i) {
            const float* xp = xg + (size_t)i * HW_;
            const float v = f00 * xp[i00] + f01 * xp[i01]
                          + f10 * xp[i10] + f11 * xp[i11];
#pragma unroll
            for (int o = 0; o < 8; ++o)
                acc[o] = fmaf(wgt[((g * 8 + o) * 8 + i) * 9 + k], v, acc[o]);
        }
    }

    unsigned short ob[8];
#pragma unroll
    for (int o = 0; o < 8; ++o) ob[o] = f2bf(acc[o]);
    *(u32x4*)(in_cl + ((size_t)b * HW_ + p) * 128 + g * 8) = *(u32x4*)ob;

#pragma unroll
    for (int i = 0; i < 8; ++i) ob[i] = f2bf(xg[(size_t)i * HW_ + p]);
    *(u32x4*)(in_cl + ((size_t)b * HW_ + p) * 128 + 64 + g * 8) = *(u32x4*)ob;
}

// ---------------------------------------------------------------------------
// MFMA conv 3x3: out[64][HW] = W[64][9*CIN] x im2col(in_cl)[9*CIN][HW].
// Block = one image row (128 px) x 64 oc, 4 waves (wave = 64oc x 32px).
// ---------------------------------------------------------------------------
template <int CIN, bool FINAL>
__global__ __launch_bounds__(256) void conv_mfma(
    const unsigned short* __restrict__ in_cl,   // [B][HW][CIN] bf16
    const unsigned short* __restrict__ wr,      // [64][9*CIN]  bf16
    const float* __restrict__ bias,             // [64]
    const unsigned short* __restrict__ resid_cl,// FINAL: [B][HW][128], ch0..63 = aligned
    float* __restrict__ outf,                   // FINAL: [B][64][HW] fp32
    unsigned short* __restrict__ outb)          // !FINAL: [B][HW][64] bf16
{
    constexpr int KTOT = CIN * 9;
    constexpr int NICC = CIN / 32;
    __shared__ unsigned short b_lds[3 * 130 * 32];   // 24960 B
    __shared__ unsigned short a_lds[9 * 64 * 32];    // 36864 B

    const int tid  = threadIdx.x;
    const int row  = blockIdx.x;
    const int b    = blockIdx.y;
    const int lane = tid & 63;
    const int l15  = lane & 15;
    const int hi   = lane >> 4;
    const int n0   = (tid >> 6) * 32;

    char* const bpc = (char*)b_lds;
    char* const apc = (char*)a_lds;

    f32x4 acc[4][2];
#pragma unroll
    for (int fm = 0; fm < 4; ++fm)
#pragma unroll
        for (int fn = 0; fn < 2; ++fn)
            acc[fm][fn] = (f32x4){0.f, 0.f, 0.f, 0.f};

    const size_t in_base = (size_t)b * HW_ * CIN;

    for (int icc = 0; icc < NICC; ++icc) {
        __syncthreads();
        // stage B tile: rows row-1..row+1, halo cols -1..128, 32 ic (16B units)
        for (int u = tid; u < 1560; u += 256) {
            const int icq = u & 3, rc = u >> 2;
            const int ri = rc / 130, hc = rc - ri * 130;
            const int gr = row + ri - 1, gc = hc - 1;
            u32x4 v = (u32x4){0u, 0u, 0u, 0u};
            if ((unsigned)gr < 128u && (unsigned)gc < 128u)
                v = *(const u32x4*)(in_cl + in_base + (size_t)(gr * 128 + gc) * CIN
                                     + icc * 32 + icq * 8);
            *(u32x4*)(bpc + (((rc * 64 + icq * 16)) ^ ((hc & 7) << 4))) = v;
        }
        // stage A chunk: 9 taps x 64 oc x 32 ic
        for (int u = tid; u < 2304; u += 256) {
            const int m = u / 36, q = u - m * 36;
            const int tap = q >> 2, icq = q & 3;
            u32x4 v = *(const u32x4*)(wr + (size_t)m * KTOT + (icc * 9 + tap) * 32 + icq * 8);
            *(u32x4*)(apc + ((((tap * 64 + m) * 64 + icq * 16)) ^ ((m & 7) << 4))) = v;
        }
        __syncthreads();

#pragma unroll
        for (int tap = 0; tap < 9; ++tap) {
            const int tr = tap / 3, tc = tap - tr * 3;
            short8 af[4], bf[2];
#pragma unroll
            for (int fm = 0; fm < 4; ++fm)
                af[fm] = *(const short8*)(apc +
                    ((((tap * 64 + fm * 16 + l15) * 64) + hi * 16) ^ ((l15 & 7) << 4)));
#pragma unroll
            for (int fn = 0; fn < 2; ++fn) {
                const int hcol = n0 + fn * 16 + l15 + tc;
                bf[fn] = *(const short8*)(bpc +
                    ((((tr * 130 + hcol) * 64) + hi * 16) ^ ((hcol & 7) << 4)));
            }
#pragma unroll
            for (int fm = 0; fm < 4; ++fm)
#pragma unroll
                for (int fn = 0; fn < 2; ++fn)
                    acc[fm][fn] = __builtin_amdgcn_mfma_f32_16x16x32_bf16(
                        af[fm], bf[fn], acc[fm][fn], 0, 0, 0);
        }
    }

    // epilogue: C/D layout col = lane&15 (pixel), row = hi*4+reg (oc)
    const int prow = row * 128;
    if (!FINAL) {
#pragma unroll
        for (int fm = 0; fm < 4; ++fm)
#pragma unroll
            for (int fn = 0; fn < 2; ++fn) {
                const int px = n0 + fn * 16 + l15;
                unsigned short o4[4];
#pragma unroll
                for (int r = 0; r < 4; ++r) {
                    const int oc = fm * 16 + hi * 4 + r;
                    float v = acc[fm][fn][r] + bias[oc];
                    v = (v >= 0.f) ? v : NEG_SLOPE * v;
                    o4[r] = f2bf(v);
                }
                *(u32x2*)(outb + ((size_t)b * HW_ + prow + px) * 64 + fm * 16 + hi * 4)
                    = *(u32x2*)o4;
            }
    } else {
#pragma unroll
        for (int fm = 0; fm < 4; ++fm)
#pragma unroll
            for (int fn = 0; fn < 2; ++fn) {
                const int px = n0 + fn * 16 + l15;
                const size_t gp = (size_t)b * HW_ + prow + px;
                u32x2 alv = *(const u32x2*)(resid_cl + gp * 128 + fm * 16 + hi * 4);
                unsigned short alu[4];
                *(u32x2*)alu = alv;
#pragma unroll
                for (int r = 0; r < 4; ++r) {
                    const int oc = fm * 16 + hi * 4 + r;
                    float v = acc[fm][fn][r] + bias[oc];
                    v = (v >= 0.f) ? v : NEG_SLOPE * v;
                    v += bf2f(alu[r]);
                    outf[((size_t)b * C_ + oc) * HW_ + prow + px] = v;
                }
            }
    }
}

// ---------------------------------------------------------------------------
extern "C" void kernel_launch(void* const* d_in, const int* in_sizes, int n_in,
                              void* d_out, int out_size, void* d_ws, size_t ws_size,
                              hipStream_t stream) {
    const float* x   = (const float*)d_in[0];
    const float* off = (const float*)d_in[1];
    const float* dw  = (const float*)d_in[2];
    const float* db  = (const float*)d_in[3];
    const float* w1  = (const float*)d_in[4];
    const float* b1  = (const float*)d_in[5];
    const float* w2  = (const float*)d_in[6];
    const float* b2  = (const float*)d_in[7];
    float* out = (float*)d_out;

    unsigned short* in_cl = (unsigned short*)d_ws;        // [2][16384][128] bf16 = 8 MB
    unsigned short* t1_cl = in_cl + (size_t)B_ * HW_ * 128; // [2][16384][64] = 4 MB
    unsigned short* w1r   = t1_cl + (size_t)B_ * HW_ * 64;  // 64*1152
    unsigned short* w2r   = w1r + 64 * 1152;                // 64*576

    prep_weights<<<288, 256, 0, stream>>>(w1, w2, w1r, w2r);
    dcn_kernel<<<dim3(HW_ / 256, 8, B_), 256, 0, stream>>>(x, off, dw, db, in_cl);
    conv_mfma<128, false><<<dim3(H_, B_), 256, 0, stream>>>(
        in_cl, w1r, b1, nullptr, nullptr, t1_cl);
    conv_mfma<64, true><<<dim3(H_, B_), 256, 0, stream>>>(
        t1_cl, w2r, b2, in_cl, out, nullptr);
}

// Round 3
// 105.367 us; speedup vs baseline: 7.2605x; 1.3039x over previous
//
#include <hip/hip_runtime.h>
#include <stdint.h>

typedef short short8 __attribute__((ext_vector_type(8)));
typedef float f32x4 __attribute__((ext_vector_type(4)));
typedef unsigned int u32x4 __attribute__((ext_vector_type(4)));
typedef unsigned int u32x2 __attribute__((ext_vector_type(2)));

constexpr int B_ = 2, C_ = 64, H_ = 128, W_ = 128, HW_ = H_ * W_;
constexpr float NEG_SLOPE = 0.1f;

__device__ inline unsigned short f2bf(float f) {
    union { float f; unsigned u; } c; c.f = f;
    unsigned r = c.u + 0x7FFFu + ((c.u >> 16) & 1u);   // RNE
    return (unsigned short)(r >> 16);
}
__device__ inline float bf2f(unsigned short s) {
    union { unsigned u; float f; } c; c.u = ((unsigned)s) << 16; return c.f;
}
__device__ inline float bflo(unsigned u) {   // low bf16 of a u32 pair
    union { unsigned u; float f; } c; c.u = u << 16; return c.f;
}
__device__ inline float bfhi(unsigned u) {   // high bf16 of a u32 pair
    union { unsigned u; float f; } c; c.u = u & 0xFFFF0000u; return c.f;
}

// ---------------------------------------------------------------------------
// Weight repack: w[oc][ic][3][3] fp32 -> wr[oc][(icc*9+tap)*32 + ici] bf16
// ---------------------------------------------------------------------------
__global__ __launch_bounds__(256) void prep_weights(
    const float* __restrict__ w1, const float* __restrict__ w2,
    unsigned short* __restrict__ w1r, unsigned short* __restrict__ w2r)
{
    const int idx = blockIdx.x * 256 + threadIdx.x;
    if (idx < 64 * 1152) {
        int oc = idx / 1152, k = idx - oc * 1152;
        int kb = k >> 5, ici = k & 31, icc = kb / 9, tap = kb - icc * 9;
        w1r[idx] = f2bf(w1[(oc * 128 + icc * 32 + ici) * 9 + tap]);
    }
    if (idx < 64 * 576) {
        int oc = idx / 576, k = idx - oc * 576;
        int kb = k >> 5, ici = k & 31, icc = kb / 9, tap = kb - icc * 9;
        w2r[idx] = f2bf(w2[(oc * 64 + icc * 32 + ici) * 9 + tap]);
    }
}

// ---------------------------------------------------------------------------
// pack_x: x [B,64,H,W] fp32 -> in_cl[b][p][64 + c] bf16 (channels-last half)
// Block: 64 pixels x 64 channels via LDS transpose (XOR-swizzled).
// ---------------------------------------------------------------------------
__global__ __launch_bounds__(256) void pack_x(
    const float* __restrict__ x, unsigned short* __restrict__ in_cl)
{
    __shared__ unsigned short t[64][72];
    const int tid = threadIdx.x;
    const int p0 = blockIdx.x * 64;
    const int b  = blockIdx.y;

#pragma unroll
    for (int u = tid; u < 4096; u += 256) {
        const int c = u >> 6, pp = u & 63;
        const unsigned short v = f2bf(x[((size_t)b * 64 + c) * HW_ + p0 + pp]);
        t[pp][c ^ ((pp & 7) << 3)] = v;
    }
    __syncthreads();
#pragma unroll
    for (int u = tid; u < 512; u += 256) {
        const int pp = u >> 3, q = u & 7;
        const u32x4 v = *(const u32x4*)&t[pp][(q ^ (pp & 7)) * 8];
        *(u32x4*)(in_cl + ((size_t)b * HW_ + p0 + pp) * 128 + 64 + q * 8) = v;
    }
}

// ---------------------------------------------------------------------------
// Deformable conv 3x3 (groups=8, offset_groups=8). Thread = (b, g, pixel),
// 8 out-channels. Samples from channels-last bf16 x (one 16B load / corner).
// Writes bf16 aligned to in_cl[p][0:64].
// ---------------------------------------------------------------------------
__global__ __launch_bounds__(256) void dcn_kernel(
    const unsigned short* __restrict__ x_cl,  // [B][HW][128], ch 64..127 = x
    const float* __restrict__ off,    // [B,144,H,W]
    const float* __restrict__ wgt,    // [64,8,3,3]
    const float* __restrict__ bias,   // [64]
    unsigned short* __restrict__ in_cl) // [B][HW][128]
{
    const int p = blockIdx.x * 256 + threadIdx.x;
    const int g = blockIdx.y;
    const int b = blockIdx.z;
    const int h = p >> 7;
    const int w = p & (W_ - 1);

    float acc[8];
#pragma unroll
    for (int o = 0; o < 8; ++o) acc[o] = bias[g * 8 + o];

    const float* offp = off + (size_t)b * 144 * HW_ + p;
    // base of this group's 8 x-channels, channels-last
    const unsigned short* xg = x_cl + (size_t)b * HW_ * 128 + 64 + g * 8;

#pragma unroll
    for (int k = 0; k < 9; ++k) {
        const float dy = offp[(size_t)((g * 9 + k) * 2 + 0) * HW_];
        const float dx = offp[(size_t)((g * 9 + k) * 2 + 1) * HW_];
        const float py = (float)(h - 1 + k / 3) + dy;
        const float px = (float)(w - 1 + k % 3) + dx;
        const float y0f = floorf(py), x0f = floorf(px);
        const int y0 = (int)y0f, x0 = (int)x0f;
        const int y1 = y0 + 1,  x1 = x0 + 1;
        const float wy = py - y0f, wx = px - x0f;

        const bool vy0 = (unsigned)y0 < (unsigned)H_;
        const bool vy1 = (unsigned)y1 < (unsigned)H_;
        const bool vx0 = (unsigned)x0 < (unsigned)W_;
        const bool vx1 = (unsigned)x1 < (unsigned)W_;

        const float f00 = (vy0 && vx0) ? (1.f - wy) * (1.f - wx) : 0.f;
        const float f01 = (vy0 && vx1) ? (1.f - wy) * wx         : 0.f;
        const float f10 = (vy1 && vx0) ? wy * (1.f - wx)         : 0.f;
        const float f11 = (vy1 && vx1) ? wy * wx                 : 0.f;

        const int cy0 = min(max(y0, 0), H_ - 1);
        const int cy1 = min(max(y1, 0), H_ - 1);
        const int cx0 = min(max(x0, 0), W_ - 1);
        const int cx1 = min(max(x1, 0), W_ - 1);

        const u32x4 c00 = *(const u32x4*)(xg + (size_t)(cy0 * W_ + cx0) * 128);
        const u32x4 c01 = *(const u32x4*)(xg + (size_t)(cy0 * W_ + cx1) * 128);
        const u32x4 c10 = *(const u32x4*)(xg + (size_t)(cy1 * W_ + cx0) * 128);
        const u32x4 c11 = *(const u32x4*)(xg + (size_t)(cy1 * W_ + cx1) * 128);

        float vf[8];
#pragma unroll
        for (int q = 0; q < 4; ++q) {
            vf[2 * q]     = f00 * bflo(c00[q]) + f01 * bflo(c01[q])
                          + f10 * bflo(c10[q]) + f11 * bflo(c11[q]);
            vf[2 * q + 1] = f00 * bfhi(c00[q]) + f01 * bfhi(c01[q])
                          + f10 * bfhi(c10[q]) + f11 * bfhi(c11[q]);
        }

#pragma unroll
        for (int i = 0; i < 8; ++i)
#pragma unroll
            for (int o = 0; o < 8; ++o)
                acc[o] = fmaf(wgt[((g * 8 + o) * 8 + i) * 9 + k], vf[i], acc[o]);
    }

    unsigned short ob[8];
#pragma unroll
    for (int o = 0; o < 8; ++o) ob[o] = f2bf(acc[o]);
    *(u32x4*)(in_cl + ((size_t)b * HW_ + p) * 128 + g * 8) = *(u32x4*)ob;
}

// ---------------------------------------------------------------------------
// MFMA conv 3x3: out[64][HW] = W[64][9*CIN] x im2col(in_cl)[9*CIN][HW].
// Block = one image row (128 px) x 64 oc, 4 waves (wave = 64oc x 32px).
// ---------------------------------------------------------------------------
template <int CIN, bool FINAL>
__global__ __launch_bounds__(256) void conv_mfma(
    const unsigned short* __restrict__ in_cl,   // [B][HW][CIN] bf16
    const unsigned short* __restrict__ wr,      // [64][9*CIN]  bf16
    const float* __restrict__ bias,             // [64]
    const unsigned short* __restrict__ resid_cl,// FINAL: [B][HW][128], ch0..63 = aligned
    float* __restrict__ outf,                   // FINAL: [B][64][HW] fp32
    unsigned short* __restrict__ outb)          // !FINAL: [B][HW][64] bf16
{
    constexpr int KTOT = CIN * 9;
    constexpr int NICC = CIN / 32;
    __shared__ unsigned short b_lds[3 * 130 * 32];   // 24960 B
    __shared__ unsigned short a_lds[9 * 64 * 32];    // 36864 B

    const int tid  = threadIdx.x;
    const int row  = blockIdx.x;
    const int b    = blockIdx.y;
    const int lane = tid & 63;
    const int l15  = lane & 15;
    const int hi   = lane >> 4;
    const int n0   = (tid >> 6) * 32;

    char* const bpc = (char*)b_lds;
    char* const apc = (char*)a_lds;

    f32x4 acc[4][2];
#pragma unroll
    for (int fm = 0; fm < 4; ++fm)
#pragma unroll
        for (int fn = 0; fn < 2; ++fn)
            acc[fm][fn] = (f32x4){0.f, 0.f, 0.f, 0.f};

    const size_t in_base = (size_t)b * HW_ * CIN;

    for (int icc = 0; icc < NICC; ++icc) {
        __syncthreads();
        // stage B tile: rows row-1..row+1, halo cols -1..128, 32 ic (16B units)
        for (int u = tid; u < 1560; u += 256) {
            const int icq = u & 3, rc = u >> 2;
            const int ri = rc / 130, hc = rc - ri * 130;
            const int gr = row + ri - 1, gc = hc - 1;
            u32x4 v = (u32x4){0u, 0u, 0u, 0u};
            if ((unsigned)gr < 128u && (unsigned)gc < 128u)
                v = *(const u32x4*)(in_cl + in_base + (size_t)(gr * 128 + gc) * CIN
                                     + icc * 32 + icq * 8);
            *(u32x4*)(bpc + (((rc * 64 + icq * 16)) ^ ((hc & 7) << 4))) = v;
        }
        // stage A chunk: 9 taps x 64 oc x 32 ic
        for (int u = tid; u < 2304; u += 256) {
            const int m = u / 36, q = u - m * 36;
            const int tap = q >> 2, icq = q & 3;
            u32x4 v = *(const u32x4*)(wr + (size_t)m * KTOT + (icc * 9 + tap) * 32 + icq * 8);
            *(u32x4*)(apc + ((((tap * 64 + m) * 64 + icq * 16)) ^ ((m & 7) << 4))) = v;
        }
        __syncthreads();

#pragma unroll
        for (int tap = 0; tap < 9; ++tap) {
            const int tr = tap / 3, tc = tap - tr * 3;
            short8 af[4], bf[2];
#pragma unroll
            for (int fm = 0; fm < 4; ++fm)
                af[fm] = *(const short8*)(apc +
                    ((((tap * 64 + fm * 16 + l15) * 64) + hi * 16) ^ ((l15 & 7) << 4)));
#pragma unroll
            for (int fn = 0; fn < 2; ++fn) {
                const int hcol = n0 + fn * 16 + l15 + tc;
                bf[fn] = *(const short8*)(bpc +
                    ((((tr * 130 + hcol) * 64) + hi * 16) ^ ((hcol & 7) << 4)));
            }
#pragma unroll
            for (int fm = 0; fm < 4; ++fm)
#pragma unroll
                for (int fn = 0; fn < 2; ++fn)
                    acc[fm][fn] = __builtin_amdgcn_mfma_f32_16x16x32_bf16(
                        af[fm], bf[fn], acc[fm][fn], 0, 0, 0);
        }
    }

    // epilogue: C/D layout col = lane&15 (pixel), row = hi*4+reg (oc)
    const int prow = row * 128;
    if (!FINAL) {
#pragma unroll
        for (int fm = 0; fm < 4; ++fm)
#pragma unroll
            for (int fn = 0; fn < 2; ++fn) {
                const int px = n0 + fn * 16 + l15;
                unsigned short o4[4];
#pragma unroll
                for (int r = 0; r < 4; ++r) {
                    const int oc = fm * 16 + hi * 4 + r;
                    float v = acc[fm][fn][r] + bias[oc];
                    v = (v >= 0.f) ? v : NEG_SLOPE * v;
                    o4[r] = f2bf(v);
                }
                *(u32x2*)(outb + ((size_t)b * HW_ + prow + px) * 64 + fm * 16 + hi * 4)
                    = *(u32x2*)o4;
            }
    } else {
#pragma unroll
        for (int fm = 0; fm < 4; ++fm)
#pragma unroll
            for (int fn = 0; fn < 2; ++fn) {
                const int px = n0 + fn * 16 + l15;
                const size_t gp = (size_t)b * HW_ + prow + px;
                u32x2 alv = *(const u32x2*)(resid_cl + gp * 128 + fm * 16 + hi * 4);
                unsigned short alu[4];
                *(u32x2*)alu = alv;
#pragma unroll
                for (int r = 0; r < 4; ++r) {
                    const int oc = fm * 16 + hi * 4 + r;
                    float v = acc[fm][fn][r] + bias[oc];
                    v = (v >= 0.f) ? v : NEG_SLOPE * v;
                    v += bf2f(alu[r]);
                    outf[((size_t)b * C_ + oc) * HW_ + prow + px] = v;
                }
            }
    }
}

// ---------------------------------------------------------------------------
extern "C" void kernel_launch(void* const* d_in, const int* in_sizes, int n_in,
                              void* d_out, int out_size, void* d_ws, size_t ws_size,
                              hipStream_t stream) {
    const float* x   = (const float*)d_in[0];
    const float* off = (const float*)d_in[1];
    const float* dw  = (const float*)d_in[2];
    const float* db  = (const float*)d_in[3];
    const float* w1  = (const float*)d_in[4];
    const float* b1  = (const float*)d_in[5];
    const float* w2  = (const float*)d_in[6];
    const float* b2  = (const float*)d_in[7];
    float* out = (float*)d_out;

    unsigned short* in_cl = (unsigned short*)d_ws;          // [2][16384][128] bf16 = 8 MB
    unsigned short* t1_cl = in_cl + (size_t)B_ * HW_ * 128; // [2][16384][64] = 4 MB
    unsigned short* w1r   = t1_cl + (size_t)B_ * HW_ * 64;  // 64*1152
    unsigned short* w2r   = w1r + 64 * 1152;                // 64*576

    prep_weights<<<288, 256, 0, stream>>>(w1, w2, w1r, w2r);
    pack_x<<<dim3(HW_ / 64, B_), 256, 0, stream>>>(x, in_cl);
    dcn_kernel<<<dim3(HW_ / 256, 8, B_), 256, 0, stream>>>(in_cl, off, dw, db, in_cl);
    conv_mfma<128, false><<<dim3(H_, B_), 256, 0, stream>>>(
        in_cl, w1r, b1, nullptr, nullptr, t1_cl);
    conv_mfma<64, true><<<dim3(H_, B_), 256, 0, stream>>>(
        t1_cl, w2r, b2, in_cl, out, nullptr);
}

// Round 4
// 103.327 us; speedup vs baseline: 7.4038x; 1.0197x over previous
//
#include <hip/hip_runtime.h>
#include <stdint.h>

typedef short short8 __attribute__((ext_vector_type(8)));
typedef float f32x4 __attribute__((ext_vector_type(4)));
typedef unsigned int u32x4 __attribute__((ext_vector_type(4)));
typedef unsigned int u32x2 __attribute__((ext_vector_type(2)));

constexpr int B_ = 2, C_ = 64, H_ = 128, W_ = 128, HW_ = H_ * W_;
constexpr float NEG_SLOPE = 0.1f;

__device__ inline unsigned short f2bf(float f) {
    union { float f; unsigned u; } c; c.f = f;
    unsigned r = c.u + 0x7FFFu + ((c.u >> 16) & 1u);   // RNE
    return (unsigned short)(r >> 16);
}
__device__ inline float bf2f(unsigned short s) {
    union { unsigned u; float f; } c; c.u = ((unsigned)s) << 16; return c.f;
}
__device__ inline float bflo(unsigned u) {
    union { unsigned u; float f; } c; c.u = u << 16; return c.f;
}
__device__ inline float bfhi(unsigned u) {
    union { unsigned u; float f; } c; c.u = u & 0xFFFF0000u; return c.f;
}

// ---------------------------------------------------------------------------
// Weight repack: w[oc][ic][3][3] fp32 -> wr[oc][(icc*9+tap)*32 + ici] bf16
// ---------------------------------------------------------------------------
__global__ __launch_bounds__(256) void prep_weights(
    const float* __restrict__ w1, const float* __restrict__ w2,
    unsigned short* __restrict__ w1r, unsigned short* __restrict__ w2r)
{
    const int idx = blockIdx.x * 256 + threadIdx.x;
    if (idx < 64 * 1152) {
        int oc = idx / 1152, k = idx - oc * 1152;
        int kb = k >> 5, ici = k & 31, icc = kb / 9, tap = kb - icc * 9;
        w1r[idx] = f2bf(w1[(oc * 128 + icc * 32 + ici) * 9 + tap]);
    }
    if (idx < 64 * 576) {
        int oc = idx / 576, k = idx - oc * 576;
        int kb = k >> 5, ici = k & 31, icc = kb / 9, tap = kb - icc * 9;
        w2r[idx] = f2bf(w2[(oc * 64 + icc * 32 + ici) * 9 + tap]);
    }
}

// ---------------------------------------------------------------------------
// pack_x: x [B,64,H,W] fp32 -> x_g[b][g][p][8] bf16 (per-group channels-last,
// 16 B per pixel-group so neighboring pixels share cache lines).
// ---------------------------------------------------------------------------
__global__ __launch_bounds__(256) void pack_x(
    const float* __restrict__ x, unsigned short* __restrict__ x_g)
{
    __shared__ unsigned short t[64][72];
    const int tid = threadIdx.x;
    const int p0 = blockIdx.x * 64;
    const int b  = blockIdx.y;

#pragma unroll
    for (int u = tid; u < 4096; u += 256) {
        const int c = u >> 6, pp = u & 63;
        t[pp][c ^ ((pp & 7) << 3)] = f2bf(x[((size_t)b * 64 + c) * HW_ + p0 + pp]);
    }
    __syncthreads();
#pragma unroll
    for (int u = tid; u < 512; u += 256) {
        const int g = u >> 6, pp = u & 63;   // consecutive lanes: same g, adjacent px
        const u32x4 v = *(const u32x4*)&t[pp][(g ^ (pp & 7)) * 8];
        *(u32x4*)(x_g + (((size_t)b * 8 + g) * HW_ + p0 + pp) * 8) = v;
    }
}

// ---------------------------------------------------------------------------
// Deformable conv 3x3 (groups=8, offset_groups=8). Thread = (b, g, pixel).
// Samples bf16 x_g (16 B per pixel); writes bf16 aligned to al_cl[p][64].
// ---------------------------------------------------------------------------
__global__ __launch_bounds__(256) void dcn_kernel(
    const unsigned short* __restrict__ x_g,   // [B][8][HW][8] bf16
    const float* __restrict__ off,    // [B,144,H,W]
    const float* __restrict__ wgt,    // [64,8,3,3]
    const float* __restrict__ bias,   // [64]
    unsigned short* __restrict__ al_cl) // [B][HW][64]
{
    const int p = blockIdx.x * 256 + threadIdx.x;
    const int g = blockIdx.y;
    const int b = blockIdx.z;
    const int h = p >> 7;
    const int w = p & (W_ - 1);

    float acc[8];
#pragma unroll
    for (int o = 0; o < 8; ++o) acc[o] = bias[g * 8 + o];

    const float* offp = off + (size_t)b * 144 * HW_ + p;
    const unsigned short* xg = x_g + ((size_t)b * 8 + g) * HW_ * 8;  // uniform base

#pragma unroll
    for (int k = 0; k < 9; ++k) {
        const float dy = offp[(size_t)((g * 9 + k) * 2 + 0) * HW_];
        const float dx = offp[(size_t)((g * 9 + k) * 2 + 1) * HW_];
        const float py = (float)(h - 1 + k / 3) + dy;
        const float px = (float)(w - 1 + k % 3) + dx;
        const float y0f = floorf(py), x0f = floorf(px);
        const int y0 = (int)y0f, x0 = (int)x0f;
        const int y1 = y0 + 1,  x1 = x0 + 1;
        const float wy = py - y0f, wx = px - x0f;

        const bool vy0 = (unsigned)y0 < (unsigned)H_;
        const bool vy1 = (unsigned)y1 < (unsigned)H_;
        const bool vx0 = (unsigned)x0 < (unsigned)W_;
        const bool vx1 = (unsigned)x1 < (unsigned)W_;

        const float f00 = (vy0 && vx0) ? (1.f - wy) * (1.f - wx) : 0.f;
        const float f01 = (vy0 && vx1) ? (1.f - wy) * wx         : 0.f;
        const float f10 = (vy1 && vx0) ? wy * (1.f - wx)         : 0.f;
        const float f11 = (vy1 && vx1) ? wy * wx                 : 0.f;

        const int cy0 = min(max(y0, 0), H_ - 1);
        const int cy1 = min(max(y1, 0), H_ - 1);
        const int cx0 = min(max(x0, 0), W_ - 1);
        const int cx1 = min(max(x1, 0), W_ - 1);

        const u32x4 c00 = *(const u32x4*)(xg + (size_t)(cy0 * W_ + cx0) * 8);
        const u32x4 c01 = *(const u32x4*)(xg + (size_t)(cy0 * W_ + cx1) * 8);
        const u32x4 c10 = *(const u32x4*)(xg + (size_t)(cy1 * W_ + cx0) * 8);
        const u32x4 c11 = *(const u32x4*)(xg + (size_t)(cy1 * W_ + cx1) * 8);

        float vf[8];
#pragma unroll
        for (int q = 0; q < 4; ++q) {
            vf[2 * q]     = f00 * bflo(c00[q]) + f01 * bflo(c01[q])
                          + f10 * bflo(c10[q]) + f11 * bflo(c11[q]);
            vf[2 * q + 1] = f00 * bfhi(c00[q]) + f01 * bfhi(c01[q])
                          + f10 * bfhi(c10[q]) + f11 * bfhi(c11[q]);
        }

#pragma unroll
        for (int i = 0; i < 8; ++i)
#pragma unroll
            for (int o = 0; o < 8; ++o)
                acc[o] = fmaf(wgt[((g * 8 + o) * 8 + i) * 9 + k], vf[i], acc[o]);
    }

    unsigned short ob[8];
#pragma unroll
    for (int o = 0; o < 8; ++o) ob[o] = f2bf(acc[o]);
    *(u32x4*)(al_cl + ((size_t)b * HW_ + p) * 64 + g * 8) = *(u32x4*)ob;
}

// ---------------------------------------------------------------------------
// MFMA conv 3x3: out[64][HW] = W[64][9*CIN] x im2col[9*CIN][HW].
// Input channels 0..63 from in0 ([B][HW][64]); for CIN=128, ch 64..127 from
// x_g ([B][8][HW][8]). Block = one image row x 64 oc, 4 waves (64oc x 32px).
// ---------------------------------------------------------------------------
template <int CIN, bool FINAL>
__global__ __launch_bounds__(256) void conv_mfma(
    const unsigned short* __restrict__ in0,     // [B][HW][64] bf16
    const unsigned short* __restrict__ x_g,     // [B][8][HW][8] bf16 (CIN=128)
    const unsigned short* __restrict__ wr,      // [64][9*CIN]  bf16
    const float* __restrict__ bias,             // [64]
    const unsigned short* __restrict__ resid_cl,// FINAL: [B][HW][64] = aligned
    float* __restrict__ outf,                   // FINAL: [B][64][HW] fp32
    unsigned short* __restrict__ outb)          // !FINAL: [B][HW][64] bf16
{
    constexpr int KTOT = CIN * 9;
    constexpr int NICC = CIN / 32;
    __shared__ unsigned short b_lds[3 * 130 * 32];   // 24960 B
    __shared__ unsigned short a_lds[9 * 64 * 32];    // 36864 B

    const int tid  = threadIdx.x;
    const int row  = blockIdx.x;
    const int b    = blockIdx.y;
    const int lane = tid & 63;
    const int l15  = lane & 15;
    const int hi   = lane >> 4;
    const int n0   = (tid >> 6) * 32;

    char* const bpc = (char*)b_lds;
    char* const apc = (char*)a_lds;

    f32x4 acc[4][2];
#pragma unroll
    for (int fm = 0; fm < 4; ++fm)
#pragma unroll
        for (int fn = 0; fn < 2; ++fn)
            acc[fm][fn] = (f32x4){0.f, 0.f, 0.f, 0.f};

    for (int icc = 0; icc < NICC; ++icc) {
        __syncthreads();
        // stage B tile: rows row-1..row+1, halo cols -1..128, 32 ic (16B units)
        for (int u = tid; u < 1560; u += 256) {
            const int icq = u & 3, rc = u >> 2;
            const int ri = rc / 130, hc = rc - ri * 130;
            const int gr = row + ri - 1, gc = hc - 1;
            u32x4 v = (u32x4){0u, 0u, 0u, 0u};
            if ((unsigned)gr < 128u && (unsigned)gc < 128u) {
                const int pix = gr * 128 + gc;
                if (icc < 2)
                    v = *(const u32x4*)(in0 + ((size_t)b * HW_ + pix) * 64
                                         + icc * 32 + icq * 8);
                else {
                    const int g = (icc - 2) * 4 + icq;
                    v = *(const u32x4*)(x_g + (((size_t)b * 8 + g) * HW_ + pix) * 8);
                }
            }
            *(u32x4*)(bpc + (((rc * 64 + icq * 16)) ^ ((hc & 7) << 4))) = v;
        }
        // stage A chunk: 9 taps x 64 oc x 32 ic
        for (int u = tid; u < 2304; u += 256) {
            const int m = u / 36, q = u - m * 36;
            const int tap = q >> 2, icq = q & 3;
            u32x4 v = *(const u32x4*)(wr + (size_t)m * KTOT + (icc * 9 + tap) * 32 + icq * 8);
            *(u32x4*)(apc + ((((tap * 64 + m) * 64 + icq * 16)) ^ ((m & 7) << 4))) = v;
        }
        __syncthreads();

#pragma unroll
        for (int tap = 0; tap < 9; ++tap) {
            const int tr = tap / 3, tc = tap - tr * 3;
            short8 af[4], bf[2];
#pragma unroll
            for (int fm = 0; fm < 4; ++fm)
                af[fm] = *(const short8*)(apc +
                    ((((tap * 64 + fm * 16 + l15) * 64) + hi * 16) ^ ((l15 & 7) << 4)));
#pragma unroll
            for (int fn = 0; fn < 2; ++fn) {
                const int hcol = n0 + fn * 16 + l15 + tc;
                bf[fn] = *(const short8*)(bpc +
                    ((((tr * 130 + hcol) * 64) + hi * 16) ^ ((hcol & 7) << 4)));
            }
#pragma unroll
            for (int fm = 0; fm < 4; ++fm)
#pragma unroll
                for (int fn = 0; fn < 2; ++fn)
                    acc[fm][fn] = __builtin_amdgcn_mfma_f32_16x16x32_bf16(
                        af[fm], bf[fn], acc[fm][fn], 0, 0, 0);
        }
    }

    // epilogue: C/D layout col = lane&15 (pixel), row = hi*4+reg (oc)
    const int prow = row * 128;
    if (!FINAL) {
#pragma unroll
        for (int fm = 0; fm < 4; ++fm)
#pragma unroll
            for (int fn = 0; fn < 2; ++fn) {
                const int px = n0 + fn * 16 + l15;
                unsigned short o4[4];
#pragma unroll
                for (int r = 0; r < 4; ++r) {
                    const int oc = fm * 16 + hi * 4 + r;
                    float v = acc[fm][fn][r] + bias[oc];
                    v = (v >= 0.f) ? v : NEG_SLOPE * v;
                    o4[r] = f2bf(v);
                }
                *(u32x2*)(outb + ((size_t)b * HW_ + prow + px) * 64 + fm * 16 + hi * 4)
                    = *(u32x2*)o4;
            }
    } else {
#pragma unroll
        for (int fm = 0; fm < 4; ++fm)
#pragma unroll
            for (int fn = 0; fn < 2; ++fn) {
                const int px = n0 + fn * 16 + l15;
                const size_t gp = (size_t)b * HW_ + prow + px;
                u32x2 alv = *(const u32x2*)(resid_cl + gp * 64 + fm * 16 + hi * 4);
                unsigned short alu[4];
                *(u32x2*)alu = alv;
#pragma unroll
                for (int r = 0; r < 4; ++r) {
                    const int oc = fm * 16 + hi * 4 + r;
                    float v = acc[fm][fn][r] + bias[oc];
                    v = (v >= 0.f) ? v : NEG_SLOPE * v;
                    v += bf2f(alu[r]);
                    outf[((size_t)b * C_ + oc) * HW_ + prow + px] = v;
                }
            }
    }
}

// ---------------------------------------------------------------------------
extern "C" void kernel_launch(void* const* d_in, const int* in_sizes, int n_in,
                              void* d_out, int out_size, void* d_ws, size_t ws_size,
                              hipStream_t stream) {
    const float* x   = (const float*)d_in[0];
    const float* off = (const float*)d_in[1];
    const float* dw  = (const float*)d_in[2];
    const float* db  = (const float*)d_in[3];
    const float* w1  = (const float*)d_in[4];
    const float* b1  = (const float*)d_in[5];
    const float* w2  = (const float*)d_in[6];
    const float* b2  = (const float*)d_in[7];
    float* out = (float*)d_out;

    unsigned short* al_cl = (unsigned short*)d_ws;            // [2][16384][64] = 4 MB
    unsigned short* x_g   = al_cl + (size_t)B_ * HW_ * 64;    // [2][8][16384][8] = 4 MB
    unsigned short* t1_cl = x_g + (size_t)B_ * HW_ * 64;      // [2][16384][64] = 4 MB
    unsigned short* w1r   = t1_cl + (size_t)B_ * HW_ * 64;    // 64*1152
    unsigned short* w2r   = w1r + 64 * 1152;                  // 64*576

    prep_weights<<<288, 256, 0, stream>>>(w1, w2, w1r, w2r);
    pack_x<<<dim3(HW_ / 64, B_), 256, 0, stream>>>(x, x_g);
    dcn_kernel<<<dim3(HW_ / 256, 8, B_), 256, 0, stream>>>(x_g, off, dw, db, al_cl);
    conv_mfma<128, false><<<dim3(H_, B_), 256, 0, stream>>>(
        al_cl, x_g, w1r, b1, nullptr, nullptr, t1_cl);
    conv_mfma<64, true><<<dim3(H_, B_), 256, 0, stream>>>(
        t1_cl, nullptr, w2r, b2, al_cl, out, nullptr);
}

// Round 5
// 69.167 us; speedup vs baseline: 11.0603x; 1.4939x over previous
//
#include <hip/hip_runtime.h>
#include <stdint.h>

typedef short short8 __attribute__((ext_vector_type(8)));
typedef float f32x4 __attribute__((ext_vector_type(4)));
typedef unsigned int u32x4 __attribute__((ext_vector_type(4)));
typedef unsigned int u32x2 __attribute__((ext_vector_type(2)));

constexpr int B_ = 2, C_ = 64, H_ = 128, W_ = 128, HW_ = H_ * W_;
constexpr float NEG_SLOPE = 0.1f;

__device__ inline unsigned short f2bf(float f) {
    union { float f; unsigned u; } c; c.f = f;
    unsigned r = c.u + 0x7FFFu + ((c.u >> 16) & 1u);   // RNE
    return (unsigned short)(r >> 16);
}
__device__ inline float bf2f(unsigned short s) {
    union { unsigned u; float f; } c; c.u = ((unsigned)s) << 16; return c.f;
}
__device__ inline float bflo(unsigned u) {
    union { unsigned u; float f; } c; c.u = u << 16; return c.f;
}
__device__ inline float bfhi(unsigned u) {
    union { unsigned u; float f; } c; c.u = u & 0xFFFF0000u; return c.f;
}

// ---------------------------------------------------------------------------
// Weight repack.
//  w1/w2 -> wr[oc][(icc*9+tap)*32+ici] bf16 (conv MFMA A source)
//  dcn w -> dwr[g][c][lane][8] bf16: A-fragment for mfma 16x16x32;
//           lane=(hi,l15): A[row=l15][k=(c*4+hi)*8+j]; rows>=8 / taps>=9 zero.
// ---------------------------------------------------------------------------
__global__ __launch_bounds__(256) void prep_weights(
    const float* __restrict__ w1, const float* __restrict__ w2,
    const float* __restrict__ dw,
    unsigned short* __restrict__ w1r, unsigned short* __restrict__ w2r,
    unsigned short* __restrict__ dwr)
{
    const int idx = blockIdx.x * 256 + threadIdx.x;
    if (idx < 64 * 1152) {
        int oc = idx / 1152, k = idx - oc * 1152;
        int kb = k >> 5, ici = k & 31, icc = kb / 9, tap = kb - icc * 9;
        w1r[idx] = f2bf(w1[(oc * 128 + icc * 32 + ici) * 9 + tap]);
    }
    if (idx < 64 * 576) {
        int oc = idx / 576, k = idx - oc * 576;
        int kb = k >> 5, ici = k & 31, icc = kb / 9, tap = kb - icc * 9;
        w2r[idx] = f2bf(w2[(oc * 64 + icc * 32 + ici) * 9 + tap]);
    }
    if (idx < 8 * 3 * 64 * 8) {
        int g = idx / 1536, r = idx - g * 1536;
        int c = r / 512, r2 = r - c * 512;
        int lane = r2 >> 3, j = r2 & 7;
        int hi = lane >> 4, l15 = lane & 15;
        int t = c * 4 + hi;
        float v = 0.f;
        if (l15 < 8 && t < 9) v = dw[((g * 8 + l15) * 8 + j) * 9 + t];
        dwr[idx] = f2bf(v);
    }
}

// ---------------------------------------------------------------------------
// pack_x: x [B,64,H,W] fp32 -> x_g[b][g][p][8] bf16 (per-group channels-last)
// ---------------------------------------------------------------------------
__global__ __launch_bounds__(256) void pack_x(
    const float* __restrict__ x, unsigned short* __restrict__ x_g)
{
    __shared__ unsigned short t[64][72];
    const int tid = threadIdx.x;
    const int p0 = blockIdx.x * 64;
    const int b  = blockIdx.y;

#pragma unroll
    for (int u = tid; u < 4096; u += 256) {
        const int c = u >> 6, pp = u & 63;
        t[pp][c ^ ((pp & 7) << 3)] = f2bf(x[((size_t)b * 64 + c) * HW_ + p0 + pp]);
    }
    __syncthreads();
#pragma unroll
    for (int u = tid; u < 512; u += 256) {
        const int g = u >> 6, pp = u & 63;
        const u32x4 v = *(const u32x4*)&t[pp][(g ^ (pp & 7)) * 8];
        *(u32x4*)(x_g + (((size_t)b * 8 + g) * HW_ + p0 + pp) * 8) = v;
    }
}

// ---------------------------------------------------------------------------
// Deformable conv via MFMA. Wave = 16 pixels x 1 group (x2 groups serial).
// Lane (hi,l15): samples taps {hi, 4+hi, 8 if hi==0} for pixel l15; its bf16
// vf[8] is the B-fragment k-chunk. A = prepacked weight fragments (dwr).
// ---------------------------------------------------------------------------
__global__ __launch_bounds__(256) void dcn_mfma(
    const unsigned short* __restrict__ x_g,   // [B][8][HW][8] bf16
    const float* __restrict__ off,            // [B,144,H,W]
    const unsigned short* __restrict__ dwr,   // [8][3][64][8] bf16
    const float* __restrict__ bias,           // [64]
    unsigned short* __restrict__ al_cl)       // [B][HW][64]
{
    const int tid  = threadIdx.x;
    const int wv   = tid >> 6;
    const int lane = tid & 63;
    const int hi   = lane >> 4;
    const int l15  = lane & 15;
    const int tile = blockIdx.x;              // 0..2047
    const int b    = tile >> 10;
    const int p    = ((tile & 1023) << 4) + l15;
    const int h    = p >> 7;
    const int w    = p & (W_ - 1);

#pragma unroll
    for (int gi = 0; gi < 2; ++gi) {
        const int g = wv + gi * 4;
        const unsigned short* xg = x_g + ((size_t)b * 8 + g) * HW_ * 8;
        const float* offp = off + ((size_t)b * 144 + g * 18) * HW_ + p;
        f32x4 acc = (f32x4){0.f, 0.f, 0.f, 0.f};

#pragma unroll
        for (int c = 0; c < 3; ++c) {
            short8 bfr = (short8){0, 0, 0, 0, 0, 0, 0, 0};
            if (c < 2 || hi == 0) {
                const int t = c * 4 + hi;
                const float dy = offp[(t * 2 + 0) * HW_];
                const float dx = offp[(t * 2 + 1) * HW_];
                const float py = (float)(h - 1 + t / 3) + dy;
                const float px = (float)(w - 1 + t % 3) + dx;
                const float y0f = floorf(py), x0f = floorf(px);
                const int y0 = (int)y0f, x0 = (int)x0f;
                const int y1 = y0 + 1,  x1 = x0 + 1;
                const float wy = py - y0f, wx = px - x0f;

                const bool vy0 = (unsigned)y0 < (unsigned)H_;
                const bool vy1 = (unsigned)y1 < (unsigned)H_;
                const bool vx0 = (unsigned)x0 < (unsigned)W_;
                const bool vx1 = (unsigned)x1 < (unsigned)W_;

                const float f00 = (vy0 && vx0) ? (1.f - wy) * (1.f - wx) : 0.f;
                const float f01 = (vy0 && vx1) ? (1.f - wy) * wx         : 0.f;
                const float f10 = (vy1 && vx0) ? wy * (1.f - wx)         : 0.f;
                const float f11 = (vy1 && vx1) ? wy * wx                 : 0.f;

                const int cy0 = min(max(y0, 0), H_ - 1);
                const int cy1 = min(max(y1, 0), H_ - 1);
                const int cx0 = min(max(x0, 0), W_ - 1);
                const int cx1 = min(max(x1, 0), W_ - 1);

                const u32x4 c00 = *(const u32x4*)(xg + (size_t)(cy0 * W_ + cx0) * 8);
                const u32x4 c01 = *(const u32x4*)(xg + (size_t)(cy0 * W_ + cx1) * 8);
                const u32x4 c10 = *(const u32x4*)(xg + (size_t)(cy1 * W_ + cx0) * 8);
                const u32x4 c11 = *(const u32x4*)(xg + (size_t)(cy1 * W_ + cx1) * 8);

                unsigned short vb[8];
#pragma unroll
                for (int q = 0; q < 4; ++q) {
                    vb[2 * q]     = f2bf(f00 * bflo(c00[q]) + f01 * bflo(c01[q])
                                       + f10 * bflo(c10[q]) + f11 * bflo(c11[q]));
                    vb[2 * q + 1] = f2bf(f00 * bfhi(c00[q]) + f01 * bfhi(c01[q])
                                       + f10 * bfhi(c10[q]) + f11 * bfhi(c11[q]));
                }
                bfr = *(const short8*)vb;
            }
            const short8 afr = *(const short8*)(dwr + ((g * 3 + c) * 64 + lane) * 8);
            acc = __builtin_amdgcn_mfma_f32_16x16x32_bf16(afr, bfr, acc, 0, 0, 0);
        }

        if (hi < 2) {
            unsigned short o4[4];
#pragma unroll
            for (int r = 0; r < 4; ++r)
                o4[r] = f2bf(acc[r] + bias[g * 8 + hi * 4 + r]);
            *(u32x2*)(al_cl + ((size_t)b * HW_ + p) * 64 + g * 8 + hi * 4) = *(u32x2*)o4;
        }
    }
}

// ---------------------------------------------------------------------------
// MFMA conv 3x3, oc-split: block = one image row x 32 oc, 4 waves.
// Grid (H, B*2). LDS 43 KB -> 2-3 blocks/CU.
// ---------------------------------------------------------------------------
template <int CIN, bool FINAL>
__global__ __launch_bounds__(256) void conv_mfma(
    const unsigned short* __restrict__ in0,     // [B][HW][64] bf16
    const unsigned short* __restrict__ x_g,     // [B][8][HW][8] bf16 (CIN=128)
    const unsigned short* __restrict__ wr,      // [64][9*CIN]  bf16
    const float* __restrict__ bias,             // [64]
    const unsigned short* __restrict__ resid_cl,// FINAL: [B][HW][64] = aligned
    float* __restrict__ outf,                   // FINAL: [B][64][HW] fp32
    unsigned short* __restrict__ outb)          // !FINAL: [B][HW][64] bf16
{
    constexpr int KTOT = CIN * 9;
    constexpr int NICC = CIN / 32;
    __shared__ unsigned short b_lds[3 * 130 * 32];   // 24960 B
    __shared__ unsigned short a_lds[9 * 32 * 32];    // 18432 B

    const int tid  = threadIdx.x;
    const int row  = blockIdx.x;
    const int zb   = blockIdx.y;
    const int b    = zb >> 1;
    const int oc0  = (zb & 1) * 32;
    const int lane = tid & 63;
    const int l15  = lane & 15;
    const int hi   = lane >> 4;
    const int n0   = (tid >> 6) * 32;

    char* const bpc = (char*)b_lds;
    char* const apc = (char*)a_lds;

    f32x4 acc[2][2];
#pragma unroll
    for (int fm = 0; fm < 2; ++fm)
#pragma unroll
        for (int fn = 0; fn < 2; ++fn)
            acc[fm][fn] = (f32x4){0.f, 0.f, 0.f, 0.f};

    for (int icc = 0; icc < NICC; ++icc) {
        __syncthreads();
        // B tile: rows row-1..row+1, halo cols -1..128, 32 ic
        for (int u = tid; u < 1560; u += 256) {
            const int icq = u & 3, rc = u >> 2;
            const int ri = rc / 130, hc = rc - ri * 130;
            const int gr = row + ri - 1, gc = hc - 1;
            u32x4 v = (u32x4){0u, 0u, 0u, 0u};
            if ((unsigned)gr < 128u && (unsigned)gc < 128u) {
                const int pix = gr * 128 + gc;
                if (icc < 2)
                    v = *(const u32x4*)(in0 + ((size_t)b * HW_ + pix) * 64
                                         + icc * 32 + icq * 8);
                else {
                    const int g = (icc - 2) * 4 + icq;
                    v = *(const u32x4*)(x_g + (((size_t)b * 8 + g) * HW_ + pix) * 8);
                }
            }
            *(u32x4*)(bpc + (((rc * 64 + icq * 16)) ^ ((hc & 7) << 4))) = v;
        }
        // A chunk: 9 taps x 32 oc x 32 ic
        for (int u = tid; u < 1152; u += 256) {
            const int ml = u / 36, q = u - ml * 36;
            const int tap = q >> 2, icq = q & 3;
            u32x4 v = *(const u32x4*)(wr + (size_t)(oc0 + ml) * KTOT
                                       + (icc * 9 + tap) * 32 + icq * 8);
            *(u32x4*)(apc + ((((tap * 32 + ml) * 64 + icq * 16)) ^ ((ml & 7) << 4))) = v;
        }
        __syncthreads();

#pragma unroll
        for (int tap = 0; tap < 9; ++tap) {
            const int tr = tap / 3, tc = tap - tr * 3;
            short8 af[2], bf[2];
#pragma unroll
            for (int fm = 0; fm < 2; ++fm)
                af[fm] = *(const short8*)(apc +
                    ((((tap * 32 + fm * 16 + l15) * 64) + hi * 16) ^ ((l15 & 7) << 4)));
#pragma unroll
            for (int fn = 0; fn < 2; ++fn) {
                const int hcol = n0 + fn * 16 + l15 + tc;
                bf[fn] = *(const short8*)(bpc +
                    ((((tr * 130 + hcol) * 64) + hi * 16) ^ ((hcol & 7) << 4)));
            }
#pragma unroll
            for (int fm = 0; fm < 2; ++fm)
#pragma unroll
                for (int fn = 0; fn < 2; ++fn)
                    acc[fm][fn] = __builtin_amdgcn_mfma_f32_16x16x32_bf16(
                        af[fm], bf[fn], acc[fm][fn], 0, 0, 0);
        }
    }

    const int prow = row * 128;
    if (!FINAL) {
#pragma unroll
        for (int fm = 0; fm < 2; ++fm)
#pragma unroll
            for (int fn = 0; fn < 2; ++fn) {
                const int px = n0 + fn * 16 + l15;
                unsigned short o4[4];
#pragma unroll
                for (int r = 0; r < 4; ++r) {
                    const int oc = oc0 + fm * 16 + hi * 4 + r;
                    float v = acc[fm][fn][r] + bias[oc];
                    v = (v >= 0.f) ? v : NEG_SLOPE * v;
                    o4[r] = f2bf(v);
                }
                *(u32x2*)(outb + ((size_t)b * HW_ + prow + px) * 64
                           + oc0 + fm * 16 + hi * 4) = *(u32x2*)o4;
            }
    } else {
#pragma unroll
        for (int fm = 0; fm < 2; ++fm)
#pragma unroll
            for (int fn = 0; fn < 2; ++fn) {
                const int px = n0 + fn * 16 + l15;
                const size_t gp = (size_t)b * HW_ + prow + px;
                u32x2 alv = *(const u32x2*)(resid_cl + gp * 64 + oc0 + fm * 16 + hi * 4);
                unsigned short alu[4];
                *(u32x2*)alu = alv;
#pragma unroll
                for (int r = 0; r < 4; ++r) {
                    const int oc = oc0 + fm * 16 + hi * 4 + r;
                    float v = acc[fm][fn][r] + bias[oc];
                    v = (v >= 0.f) ? v : NEG_SLOPE * v;
                    v += bf2f(alu[r]);
                    outf[((size_t)b * C_ + oc) * HW_ + prow + px] = v;
                }
            }
    }
}

// ---------------------------------------------------------------------------
extern "C" void kernel_launch(void* const* d_in, const int* in_sizes, int n_in,
                              void* d_out, int out_size, void* d_ws, size_t ws_size,
                              hipStream_t stream) {
    const float* x   = (const float*)d_in[0];
    const float* off = (const float*)d_in[1];
    const float* dw  = (const float*)d_in[2];
    const float* db  = (const float*)d_in[3];
    const float* w1  = (const float*)d_in[4];
    const float* b1  = (const float*)d_in[5];
    const float* w2  = (const float*)d_in[6];
    const float* b2  = (const float*)d_in[7];
    float* out = (float*)d_out;

    unsigned short* al_cl = (unsigned short*)d_ws;            // [2][16384][64] = 4 MB
    unsigned short* x_g   = al_cl + (size_t)B_ * HW_ * 64;    // [2][8][16384][8] = 4 MB
    unsigned short* t1_cl = x_g + (size_t)B_ * HW_ * 64;      // [2][16384][64] = 4 MB
    unsigned short* w1r   = t1_cl + (size_t)B_ * HW_ * 64;    // 64*1152
    unsigned short* w2r   = w1r + 64 * 1152;                  // 64*576
    unsigned short* dwr   = w2r + 64 * 576;                   // 8*3*64*8

    prep_weights<<<288, 256, 0, stream>>>(w1, w2, dw, w1r, w2r, dwr);
    pack_x<<<dim3(HW_ / 64, B_), 256, 0, stream>>>(x, x_g);
    dcn_mfma<<<B_ * HW_ / 16, 256, 0, stream>>>(x_g, off, dwr, db, al_cl);
    conv_mfma<128, false><<<dim3(H_, B_ * 2), 256, 0, stream>>>(
        al_cl, x_g, w1r, b1, nullptr, nullptr, t1_cl);
    conv_mfma<64, true><<<dim3(H_, B_ * 2), 256, 0, stream>>>(
        t1_cl, nullptr, w2r, b2, al_cl, out, nullptr);
}

// Round 6
// 57.354 us; speedup vs baseline: 13.3383x; 1.2060x over previous
//
#include <hip/hip_runtime.h>
#include <stdint.h>

typedef short short8 __attribute__((ext_vector_type(8)));
typedef float f32x4 __attribute__((ext_vector_type(4)));
typedef unsigned int u32x4 __attribute__((ext_vector_type(4)));
typedef unsigned int u32x2 __attribute__((ext_vector_type(2)));

constexpr int B_ = 2, C_ = 64, H_ = 128, W_ = 128, HW_ = H_ * W_;
constexpr float NEG_SLOPE = 0.1f;

__device__ inline unsigned short f2bf(float f) {
    union { float f; unsigned u; } c; c.f = f;
    unsigned r = c.u + 0x7FFFu + ((c.u >> 16) & 1u);   // RNE
    return (unsigned short)(r >> 16);
}
__device__ inline float bf2f(unsigned short s) {
    union { unsigned u; float f; } c; c.u = ((unsigned)s) << 16; return c.f;
}
__device__ inline float bflo(unsigned u) {
    union { unsigned u; float f; } c; c.u = u << 16; return c.f;
}
__device__ inline float bfhi(unsigned u) {
    union { unsigned u; float f; } c; c.u = u & 0xFFFF0000u; return c.f;
}

// ---------------------------------------------------------------------------
// prep_pack: fused weight repack + x transpose.
//  bx <  512: pack x [B,64,H,W] fp32 -> x_g[b][g][p][8] bf16
//  bx >= 512: w1/w2 -> wa[kstep][oc][ici] bf16 (k-major, coalesced A-frags)
//             dcn w -> dwr[g][c][lane][8] bf16 (prepacked A-fragments)
// ---------------------------------------------------------------------------
__global__ __launch_bounds__(256) void prep_pack(
    const float* __restrict__ x,  const float* __restrict__ w1,
    const float* __restrict__ w2, const float* __restrict__ dw,
    unsigned short* __restrict__ x_g, unsigned short* __restrict__ w1a,
    unsigned short* __restrict__ w2a, unsigned short* __restrict__ dwr)
{
    __shared__ unsigned short t[64][72];
    const int bx = blockIdx.x;
    const int tid = threadIdx.x;

    if (bx < 512) {
        const int b  = bx >> 8;
        const int p0 = (bx & 255) * 64;
#pragma unroll
        for (int u = tid; u < 4096; u += 256) {
            const int c = u >> 6, pp = u & 63;
            t[pp][c ^ ((pp & 7) << 3)] = f2bf(x[((size_t)b * 64 + c) * HW_ + p0 + pp]);
        }
        __syncthreads();
#pragma unroll
        for (int u = tid; u < 512; u += 256) {
            const int g = u >> 6, pp = u & 63;
            const u32x4 v = *(const u32x4*)&t[pp][(g ^ (pp & 7)) * 8];
            *(u32x4*)(x_g + (((size_t)b * 8 + g) * HW_ + p0 + pp) * 8) = v;
        }
        return;
    }

    const int idx = (bx - 512) * 256 + tid;
    if (idx < 64 * 1152) {            // w1a[(icc*9+tap)*64 + oc][ici]
        const int ici = idx & 31, t2 = idx >> 5;
        const int oc = t2 & 63, ks = t2 >> 6;
        const int icc = ks / 9, tap = ks - icc * 9;
        w1a[idx] = f2bf(w1[(oc * 128 + icc * 32 + ici) * 9 + tap]);
    }
    if (idx < 64 * 576) {             // w2a[(icc*9+tap)*64 + oc][ici]
        const int ici = idx & 31, t2 = idx >> 5;
        const int oc = t2 & 63, ks = t2 >> 6;
        const int icc = ks / 9, tap = ks - icc * 9;
        w2a[idx] = f2bf(w2[(oc * 64 + icc * 32 + ici) * 9 + tap]);
    }
    if (idx < 8 * 3 * 64 * 8) {       // dwr[g][c][lane][8]
        const int g = idx / 1536, r = idx - g * 1536;
        const int c = r / 512, r2 = r - c * 512;
        const int lane = r2 >> 3, j = r2 & 7;
        const int hi = lane >> 4, l15 = lane & 15;
        const int tp = c * 4 + hi;
        float v = 0.f;
        if (l15 < 8 && tp < 9) v = dw[((g * 8 + l15) * 8 + j) * 9 + tp];
        dwr[idx] = f2bf(v);
    }
}

// ---------------------------------------------------------------------------
// Deformable conv via MFMA. Wave = 16 pixels x 1 group (x2 groups serial).
// ---------------------------------------------------------------------------
__global__ __launch_bounds__(256) void dcn_mfma(
    const unsigned short* __restrict__ x_g,   // [B][8][HW][8] bf16
    const float* __restrict__ off,            // [B,144,H,W]
    const unsigned short* __restrict__ dwr,   // [8][3][64][8] bf16
    const float* __restrict__ bias,           // [64]
    unsigned short* __restrict__ al_cl)       // [B][HW][64]
{
    const int tid  = threadIdx.x;
    const int wv   = tid >> 6;
    const int lane = tid & 63;
    const int hi   = lane >> 4;
    const int l15  = lane & 15;
    const int tile = blockIdx.x;              // 0..2047
    const int b    = tile >> 10;
    const int p    = ((tile & 1023) << 4) + l15;
    const int h    = p >> 7;
    const int w    = p & (W_ - 1);

#pragma unroll
    for (int gi = 0; gi < 2; ++gi) {
        const int g = wv + gi * 4;
        const unsigned short* xg = x_g + ((size_t)b * 8 + g) * HW_ * 8;
        const float* offp = off + ((size_t)b * 144 + g * 18) * HW_ + p;
        f32x4 acc = (f32x4){0.f, 0.f, 0.f, 0.f};

#pragma unroll
        for (int c = 0; c < 3; ++c) {
            short8 bfr = (short8){0, 0, 0, 0, 0, 0, 0, 0};
            if (c < 2 || hi == 0) {
                const int t = c * 4 + hi;
                const float dy = offp[(t * 2 + 0) * HW_];
                const float dx = offp[(t * 2 + 1) * HW_];
                const float py = (float)(h - 1 + t / 3) + dy;
                const float px = (float)(w - 1 + t % 3) + dx;
                const float y0f = floorf(py), x0f = floorf(px);
                const int y0 = (int)y0f, x0 = (int)x0f;
                const int y1 = y0 + 1,  x1 = x0 + 1;
                const float wy = py - y0f, wx = px - x0f;

                const bool vy0 = (unsigned)y0 < (unsigned)H_;
                const bool vy1 = (unsigned)y1 < (unsigned)H_;
                const bool vx0 = (unsigned)x0 < (unsigned)W_;
                const bool vx1 = (unsigned)x1 < (unsigned)W_;

                const float f00 = (vy0 && vx0) ? (1.f - wy) * (1.f - wx) : 0.f;
                const float f01 = (vy0 && vx1) ? (1.f - wy) * wx         : 0.f;
                const float f10 = (vy1 && vx0) ? wy * (1.f - wx)         : 0.f;
                const float f11 = (vy1 && vx1) ? wy * wx                 : 0.f;

                const int cy0 = min(max(y0, 0), H_ - 1);
                const int cy1 = min(max(y1, 0), H_ - 1);
                const int cx0 = min(max(x0, 0), W_ - 1);
                const int cx1 = min(max(x1, 0), W_ - 1);

                const u32x4 c00 = *(const u32x4*)(xg + (size_t)(cy0 * W_ + cx0) * 8);
                const u32x4 c01 = *(const u32x4*)(xg + (size_t)(cy0 * W_ + cx1) * 8);
                const u32x4 c10 = *(const u32x4*)(xg + (size_t)(cy1 * W_ + cx0) * 8);
                const u32x4 c11 = *(const u32x4*)(xg + (size_t)(cy1 * W_ + cx1) * 8);

                unsigned short vb[8];
#pragma unroll
                for (int q = 0; q < 4; ++q) {
                    vb[2 * q]     = f2bf(f00 * bflo(c00[q]) + f01 * bflo(c01[q])
                                       + f10 * bflo(c10[q]) + f11 * bflo(c11[q]));
                    vb[2 * q + 1] = f2bf(f00 * bfhi(c00[q]) + f01 * bfhi(c01[q])
                                       + f10 * bfhi(c10[q]) + f11 * bfhi(c11[q]));
                }
                bfr = *(const short8*)vb;
            }
            const short8 afr = *(const short8*)(dwr + ((g * 3 + c) * 64 + lane) * 8);
            acc = __builtin_amdgcn_mfma_f32_16x16x32_bf16(afr, bfr, acc, 0, 0, 0);
        }

        if (hi < 2) {
            unsigned short o4[4];
#pragma unroll
            for (int r = 0; r < 4; ++r)
                o4[r] = f2bf(acc[r] + bias[g * 8 + hi * 4 + r]);
            *(u32x2*)(al_cl + ((size_t)b * HW_ + p) * 64 + g * 8 + hi * 4) = *(u32x2*)o4;
        }
    }
}

// ---------------------------------------------------------------------------
// MFMA conv 3x3 v2: A-fragments straight from global (k-major wa, coalesced,
// L2-resident); B double-buffered in LDS, ONE barrier per 32-ic chunk.
// Block = 4 waves = 64 oc x 64 px (wave: (tid>>7) oc-half x (tid>>6)&1 px-half).
// Grid (2 col-tiles, 128 rows, B).
// ---------------------------------------------------------------------------
template <int CIN, bool FINAL>
__global__ __launch_bounds__(256) void conv_mfma(
    const unsigned short* __restrict__ in0,     // [B][HW][64] bf16
    const unsigned short* __restrict__ x_g,     // [B][8][HW][8] bf16 (CIN=128)
    const unsigned short* __restrict__ wa,      // [NICC*9][64][32] bf16 k-major
    const float* __restrict__ bias,             // [64]
    const unsigned short* __restrict__ resid_cl,// FINAL: [B][HW][64] = aligned
    float* __restrict__ outf,                   // FINAL: [B][64][HW] fp32
    unsigned short* __restrict__ outb)          // !FINAL: [B][HW][64] bf16
{
    constexpr int NICC = CIN / 32;
    __shared__ unsigned short b_lds[2][3 * 66 * 32];   // 2 x 12672 B

    const int tid  = threadIdx.x;
    const int lane = tid & 63;
    const int l15  = lane & 15;
    const int hi   = lane >> 4;
    const int wp   = (tid >> 6) & 1;   // px half
    const int wo   = tid >> 7;         // oc half
    const int ct   = blockIdx.x;
    const int row  = blockIdx.y;
    const int b    = blockIdx.z;
    const int col0 = ct * 64;
    const int oc0w = wo * 32;

    f32x4 acc[2][2];
#pragma unroll
    for (int fm = 0; fm < 2; ++fm)
#pragma unroll
        for (int fn = 0; fn < 2; ++fn)
            acc[fm][fn] = (f32x4){0.f, 0.f, 0.f, 0.f};

    u32x4 sreg[4];

    auto ldregs = [&](int icc) {
#pragma unroll
        for (int t = 0; t < 4; ++t) {
            const int u = tid + t * 256;
            u32x4 v = (u32x4){0u, 0u, 0u, 0u};
            if (u < 792) {
                const int icq = u & 3, rc = u >> 2;       // rc = ri*66 + hc
                const int ri = rc / 66, hc = rc - ri * 66;
                const int gr = row + ri - 1, gc = col0 + hc - 1;
                if ((unsigned)gr < 128u && (unsigned)gc < 128u) {
                    const int pix = gr * 128 + gc;
                    if (CIN == 64 || icc < 2)
                        v = *(const u32x4*)(in0 + ((size_t)b * HW_ + pix) * 64
                                             + icc * 32 + icq * 8);
                    else {
                        const int g = (icc - 2) * 4 + icq;
                        v = *(const u32x4*)(x_g + (((size_t)b * 8 + g) * HW_ + pix) * 8);
                    }
                }
            }
            sreg[t] = v;
        }
    };

    auto dswrite = [&](int buf) {
        char* bp = (char*)b_lds[buf];
#pragma unroll
        for (int t = 0; t < 4; ++t) {
            const int u = tid + t * 256;
            if (u < 792) {
                const int icq = u & 3, rc = u >> 2;
                const int hc = rc % 66;
                *(u32x4*)(bp + ((rc * 64 + icq * 16) ^ ((hc & 7) << 4))) = sreg[t];
            }
        }
    };

    auto compute = [&](int icc, int buf) {
        const char* bp = (const char*)b_lds[buf];
#pragma unroll
        for (int tap = 0; tap < 9; ++tap) {
            const int tr = tap / 3, tc = tap - tr * 3;
            short8 af[2], bfr[2];
#pragma unroll
            for (int fm = 0; fm < 2; ++fm)
                af[fm] = *(const short8*)(wa +
                    ((size_t)((icc * 9 + tap) * 64) + oc0w + fm * 16 + l15) * 32 + hi * 8);
#pragma unroll
            for (int fn = 0; fn < 2; ++fn) {
                const int hcol = wp * 32 + fn * 16 + l15 + tc;
                bfr[fn] = *(const short8*)(bp +
                    (((tr * 66 + hcol) * 64 + hi * 16) ^ ((hcol & 7) << 4)));
            }
#pragma unroll
            for (int fm = 0; fm < 2; ++fm)
#pragma unroll
                for (int fn = 0; fn < 2; ++fn)
                    acc[fm][fn] = __builtin_amdgcn_mfma_f32_16x16x32_bf16(
                        af[fm], bfr[fn], acc[fm][fn], 0, 0, 0);
        }
    };

    ldregs(0);
    dswrite(0);
    __syncthreads();
#pragma unroll
    for (int icc = 0; icc < NICC; ++icc) {
        if (icc + 1 < NICC) ldregs(icc + 1);
        compute(icc, icc & 1);
        if (icc + 1 < NICC) {
            dswrite((icc + 1) & 1);
            __syncthreads();
        }
    }

    // epilogue: C/D layout col = lane&15 (pixel), row = hi*4+reg (oc)
    const int prow = row * 128 + col0 + wp * 32;
    if (!FINAL) {
#pragma unroll
        for (int fm = 0; fm < 2; ++fm)
#pragma unroll
            for (int fn = 0; fn < 2; ++fn) {
                const int px = prow + fn * 16 + l15;
                unsigned short o4[4];
#pragma unroll
                for (int r = 0; r < 4; ++r) {
                    const int oc = oc0w + fm * 16 + hi * 4 + r;
                    float v = acc[fm][fn][r] + bias[oc];
                    v = (v >= 0.f) ? v : NEG_SLOPE * v;
                    o4[r] = f2bf(v);
                }
                *(u32x2*)(outb + ((size_t)b * HW_ + px) * 64 + oc0w + fm * 16 + hi * 4)
                    = *(u32x2*)o4;
            }
    } else {
#pragma unroll
        for (int fm = 0; fm < 2; ++fm)
#pragma unroll
            for (int fn = 0; fn < 2; ++fn) {
                const int px = prow + fn * 16 + l15;
                const size_t gp = (size_t)b * HW_ + px;
                u32x2 alv = *(const u32x2*)(resid_cl + gp * 64 + oc0w + fm * 16 + hi * 4);
                unsigned short alu[4];
                *(u32x2*)alu = alv;
#pragma unroll
                for (int r = 0; r < 4; ++r) {
                    const int oc = oc0w + fm * 16 + hi * 4 + r;
                    float v = acc[fm][fn][r] + bias[oc];
                    v = (v >= 0.f) ? v : NEG_SLOPE * v;
                    v += bf2f(alu[r]);
                    outf[((size_t)b * C_ + oc) * HW_ + px] = v;
                }
            }
    }
}

// ---------------------------------------------------------------------------
extern "C" void kernel_launch(void* const* d_in, const int* in_sizes, int n_in,
                              void* d_out, int out_size, void* d_ws, size_t ws_size,
                              hipStream_t stream) {
    const float* x   = (const float*)d_in[0];
    const float* off = (const float*)d_in[1];
    const float* dw  = (const float*)d_in[2];
    const float* db  = (const float*)d_in[3];
    const float* w1  = (const float*)d_in[4];
    const float* b1  = (const float*)d_in[5];
    const float* w2  = (const float*)d_in[6];
    const float* b2  = (const float*)d_in[7];
    float* out = (float*)d_out;

    unsigned short* al_cl = (unsigned short*)d_ws;            // [2][16384][64] = 4 MB
    unsigned short* x_g   = al_cl + (size_t)B_ * HW_ * 64;    // [2][8][16384][8] = 4 MB
    unsigned short* t1_cl = x_g + (size_t)B_ * HW_ * 64;      // [2][16384][64] = 4 MB
    unsigned short* w1a   = t1_cl + (size_t)B_ * HW_ * 64;    // 64*1152
    unsigned short* w2a   = w1a + 64 * 1152;                  // 64*576
    unsigned short* dwr   = w2a + 64 * 576;                   // 8*3*64*8

    prep_pack<<<512 + 288, 256, 0, stream>>>(x, w1, w2, dw, x_g, w1a, w2a, dwr);
    dcn_mfma<<<B_ * HW_ / 16, 256, 0, stream>>>(x_g, off, dwr, db, al_cl);
    conv_mfma<128, false><<<dim3(2, H_, B_), 256, 0, stream>>>(
        al_cl, x_g, w1a, b1, nullptr, nullptr, t1_cl);
    conv_mfma<64, true><<<dim3(2, H_, B_), 256, 0, stream>>>(
        t1_cl, nullptr, w2a, b2, al_cl, out, nullptr);
}